// Round 8
// baseline (782.074 us; speedup 1.0000x reference)
//
#include <hip/hip_runtime.h>
#include <math.h>

// Problem constants
#define BB   16
#define CCH  512
#define HWN  4608      // H*W = 96*48
#define HW4  1152      // HWN/4
#define NSE  32
#define BN_EPS 1e-5f

#define NCH  8         // channel chunks in k_proj
#define CPC  64        // channels per chunk

typedef float f32x4 __attribute__((ext_vector_type(4)));

// ---------------------------------------------------------------------------
// K1: xp[b,c] = spatial mean (2048 blocks x 256 thr, 1 wave/row).
// The last block of each batch (counter) computes the SE gate and emits
// gate-folded projection weights. Device-scope fences per Guideline 16.
// ---------------------------------------------------------------------------
__global__ __launch_bounds__(256) void k_mean_gate(
    const float* __restrict__ x,
    const float* __restrict__ se_w1, const float* __restrict__ se_b1,
    const float* __restrict__ se_w2, const float* __restrict__ se_b2,
    const float* __restrict__ g_w, const float* __restrict__ theta_w,
    const float* __restrict__ phi_w,
    float* __restrict__ xp, float* __restrict__ tw, float* __restrict__ pw,
    float* __restrict__ gw, unsigned int* __restrict__ cnt)
{
    __shared__ float xs[CCH];
    __shared__ float hs[NSE];
    __shared__ unsigned int lastflag;
    int t = threadIdx.x;
    int wave = t >> 6, lane = t & 63;
    int row = blockIdx.x * 4 + wave;         // 4 rows/block, same b (128 blk/b)
    int b = row >> 9;
    const float4* xr = (const float4*)x + (size_t)row * HW4;
    float s = 0.f;
    #pragma unroll
    for (int k = 0; k < 18; ++k) {
        float4 v = xr[lane + k * 64];
        s += v.x + v.y + v.z + v.w;
    }
    #pragma unroll
    for (int off = 32; off > 0; off >>= 1)
        s += __shfl_down(s, off);
    if (lane == 0) xp[row] = s * (1.0f / (float)HWN);

    // completion: last block of this batch does the gate
    __threadfence();                          // release xp stores (agent scope)
    __syncthreads();
    if (t == 0) lastflag = (atomicAdd(&cnt[b], 1u) == 127u) ? 1u : 0u;
    __syncthreads();
    if (!lastflag) return;
    __threadfence();                          // acquire other blocks' xp

    xs[t]       = xp[b * CCH + t];
    xs[t + 256] = xp[b * CCH + 256 + t];
    __syncthreads();
    #pragma unroll
    for (int i = 0; i < 8; ++i) {
        int h = wave * 8 + i;                 // 4 waves x 8 = 32 hidden units
        const float* wr = se_w1 + h * CCH;
        float a = 0.f;
        #pragma unroll
        for (int k = 0; k < 8; ++k)
            a += wr[lane + 64 * k] * xs[lane + 64 * k];
        #pragma unroll
        for (int off = 32; off > 0; off >>= 1)
            a += __shfl_down(a, off);
        if (lane == 0) {
            a += se_b1[h];
            hs[h] = a > 0.f ? a : 0.f;        // relu
        }
    }
    __syncthreads();
    #pragma unroll
    for (int cc = 0; cc < 2; ++cc) {
        int c = t + cc * 256;
        float a = se_b2[c];
        const float* wr = se_w2 + c * NSE;
        #pragma unroll
        for (int j = 0; j < NSE; ++j) a += wr[j] * hs[j];
        float gate = 1.f / (1.f + expf(-a));  // sigmoid
        int idx = b * CCH + c;
        tw[idx] = gate * theta_w[c];
        pw[idx] = gate * phi_w[c];
        gw[idx] = gate * g_w[c];
    }
}

// ---------------------------------------------------------------------------
// K2: partial channel contractions (grid (9, 8, 16) x 128 thr, float4 loads).
// The last block of each batch reduces s[b] and writes ths[b,:].
// ---------------------------------------------------------------------------
__global__ __launch_bounds__(128) void k_proj_s(
    const float* __restrict__ x,
    const float* __restrict__ tw, const float* __restrict__ pw,
    const float* __restrict__ gw,
    const float* __restrict__ theta_b, const float* __restrict__ phi_b,
    const float* __restrict__ g_b,
    float* __restrict__ th_part, float* __restrict__ ph_part,
    float* __restrict__ gx_part, float* __restrict__ ths,
    unsigned int* __restrict__ cnt)
{
    __shared__ float tws[CPC], pws[CPC], gws[CPC];
    __shared__ float red[2];
    __shared__ float s_sh;
    __shared__ unsigned int lastflag;
    int t = threadIdx.x;
    int b = blockIdx.z;
    int ch = blockIdx.y;
    int c0 = ch * CPC;
    int p4 = blockIdx.x * 128 + t;           // float4 index within row
    if (t < CPC) {
        int wi = b * CCH + c0 + t;
        tws[t] = tw[wi]; pws[t] = pw[wi]; gws[t] = gw[wi];
    }
    __syncthreads();
    const float4* xr = (const float4*)x + (size_t)(b * CCH + c0) * HW4 + p4;
    float4 tha = {0.f, 0.f, 0.f, 0.f};
    float4 pha = {0.f, 0.f, 0.f, 0.f};
    float4 gxa = {0.f, 0.f, 0.f, 0.f};
    #pragma unroll 8
    for (int c = 0; c < CPC; ++c) {
        float4 v = xr[(size_t)c * HW4];      // 128 lanes x 16B contiguous
        float tc = tws[c], pc = pws[c], gc = gws[c];
        tha.x += tc * v.x; tha.y += tc * v.y; tha.z += tc * v.z; tha.w += tc * v.w;
        pha.x += pc * v.x; pha.y += pc * v.y; pha.z += pc * v.z; pha.w += pc * v.w;
        gxa.x += gc * v.x; gxa.y += gc * v.y; gxa.z += gc * v.z; gxa.w += gc * v.w;
    }
    size_t oi = (size_t)(ch * BB + b) * HW4 + p4;
    ((float4*)th_part)[oi] = tha;
    ((float4*)ph_part)[oi] = pha;
    ((float4*)gx_part)[oi] = gxa;

    // completion: last of the 72 blocks of this batch does s + ths
    __threadfence();
    __syncthreads();
    if (t == 0) lastflag = (atomicAdd(&cnt[b], 1u) == 71u) ? 1u : 0u;
    __syncthreads();
    if (!lastflag) return;
    __threadfence();

    float pb = phi_b[0], gb = g_b[0];
    const float4* php = (const float4*)ph_part;
    const float4* gxp = (const float4*)gx_part;
    float acc = 0.f;
    for (int i = t; i < HW4; i += 128) {
        float4 ph = {pb, pb, pb, pb};
        float4 gx = {gb, gb, gb, gb};
        #pragma unroll
        for (int k = 0; k < NCH; ++k) {
            size_t q = (size_t)(k * BB + b) * HW4 + i;
            float4 pv = php[q];
            float4 gv = gxp[q];
            ph.x += pv.x; ph.y += pv.y; ph.z += pv.z; ph.w += pv.w;
            gx.x += gv.x; gx.y += gv.y; gx.z += gv.z; gx.w += gv.w;
        }
        acc += ph.x * gx.x + ph.y * gx.y + ph.z * gx.z + ph.w * gx.w;
    }
    #pragma unroll
    for (int off = 32; off > 0; off >>= 1)
        acc += __shfl_down(acc, off);
    if ((t & 63) == 0) red[t >> 6] = acc;
    __syncthreads();
    if (t == 0) s_sh = (red[0] + red[1]) * (1.0f / (float)HWN);
    __syncthreads();
    float s = s_sh;
    float tb = theta_b[0];
    const float4* thp = (const float4*)th_part;
    for (int i = t; i < HW4; i += 128) {
        float4 th = {tb, tb, tb, tb};
        #pragma unroll
        for (int k = 0; k < NCH; ++k) {
            float4 tv = thp[(size_t)(k * BB + b) * HW4 + i];
            th.x += tv.x; th.y += tv.y; th.z += tv.z; th.w += tv.w;
        }
        float4 o = {th.x * s, th.y * s, th.z * s, th.w * s};
        ((float4*)ths)[(size_t)b * HW4 + i] = o;
    }
}

// ---------------------------------------------------------------------------
// K3: out[b,c,p] = x[b,c,p] + ths[b,p]*A[c] + D[c]
// 2048 blocks x 256 thr, one wave per channel row, nontemporal stores.
// ---------------------------------------------------------------------------
__global__ __launch_bounds__(256) void k_out(
    const float* __restrict__ x, const float* __restrict__ ths,
    const float* __restrict__ W_w, const float* __restrict__ W_b,
    const float* __restrict__ bn_gamma, const float* __restrict__ bn_beta,
    const float* __restrict__ bn_mean, const float* __restrict__ bn_var,
    float* __restrict__ out) {
    int wave = threadIdx.x >> 6;
    int lane = threadIdx.x & 63;
    int c = blockIdx.x * 4 + wave;
    int b = blockIdx.y;
    float inv = bn_gamma[c] * rsqrtf(bn_var[c] + BN_EPS);
    float A = W_w[c] * inv;
    float Dc = (W_b[c] - bn_mean[c]) * inv + bn_beta[c];
    const float4* xr = (const float4*)x + (size_t)(b * CCH + c) * HW4;
    const float4* tr = (const float4*)ths + (size_t)b * HW4;
    f32x4* orow = (f32x4*)out + (size_t)(b * CCH + c) * HW4;
    #pragma unroll
    for (int k = 0; k < 18; ++k) {
        int i = lane + k * 64;
        float4 xv = xr[i];
        float4 tv = tr[i];
        f32x4 o;
        o.x = xv.x + tv.x * A + Dc;
        o.y = xv.y + tv.y * A + Dc;
        o.z = xv.z + tv.z * A + Dc;
        o.w = xv.w + tv.w * A + Dc;
        __builtin_nontemporal_store(o, &orow[i]);
    }
}

// ---------------------------------------------------------------------------
extern "C" void kernel_launch(void* const* d_in, const int* in_sizes, int n_in,
                              void* d_out, int out_size, void* d_ws, size_t ws_size,
                              hipStream_t stream) {
    const float* x       = (const float*)d_in[0];
    const float* se_w1   = (const float*)d_in[1];
    const float* se_b1   = (const float*)d_in[2];
    const float* se_w2   = (const float*)d_in[3];
    const float* se_b2   = (const float*)d_in[4];
    const float* g_w     = (const float*)d_in[5];
    const float* g_b     = (const float*)d_in[6];
    const float* theta_w = (const float*)d_in[7];
    const float* theta_b = (const float*)d_in[8];
    const float* phi_w   = (const float*)d_in[9];
    const float* phi_b   = (const float*)d_in[10];
    const float* W_w     = (const float*)d_in[11];
    const float* W_b     = (const float*)d_in[12];
    const float* bn_g    = (const float*)d_in[13];
    const float* bn_b    = (const float*)d_in[14];
    const float* bn_m    = (const float*)d_in[15];
    const float* bn_v    = (const float*)d_in[16];
    float* out = (float*)d_out;

    // workspace layout (float offsets) — ~7.5 MB of the ~576 MB workspace
    float* ws      = (float*)d_ws;
    float* xp      = ws;                          // 8192
    float* tw      = ws + 8192;                   // 8192
    float* pw      = ws + 16384;                  // 8192
    float* gwv     = ws + 24576;                  // 8192
    float* th_part = ws + 32768;                  // 8*16*4608 = 589824
    float* ph_part = ws + 32768 + 589824;         // 589824
    float* gx_part = ws + 32768 + 2 * 589824;     // 589824
    float* ths     = ws + 32768 + 3 * 589824;     // 73728
    unsigned int* cnt = (unsigned int*)(ths + 73728);  // 2*16 uints (aligned)

    // zero completion counters (capture-safe async memset, 128 B)
    hipMemsetAsync(cnt, 0, 32 * sizeof(unsigned int), stream);

    k_mean_gate<<<BB * CCH / 4, 256, 0, stream>>>(
        x, se_w1, se_b1, se_w2, se_b2, g_w, theta_w, phi_w,
        xp, tw, pw, gwv, cnt);
    dim3 gc(9, NCH, BB);
    k_proj_s<<<gc, 128, 0, stream>>>(
        x, tw, pw, gwv, theta_b, phi_b, g_b,
        th_part, ph_part, gx_part, ths, cnt + BB);
    dim3 gd(CCH / 4, BB);
    k_out<<<gd, 256, 0, stream>>>(x, ths, W_w, W_b, bn_g, bn_b, bn_m, bn_v, out);
}

// Round 9
// 340.102 us; speedup vs baseline: 2.2995x; 2.2995x over previous
//
#include <hip/hip_runtime.h>
#include <math.h>

// Problem constants
#define BB   16
#define CCH  512
#define HWN  4608      // H*W = 96*48
#define HW4  1152      // HWN/4
#define NSE  32
#define BN_EPS 1e-5f

#define NCH  8         // channel chunks in k_proj
#define CPC  64        // channels per chunk

typedef float f32x4 __attribute__((ext_vector_type(4)));

// ---------------------------------------------------------------------------
// Pass 1: xp[b,c] = spatial mean. 2048 blocks x 256 thr, one wave per row.
// ---------------------------------------------------------------------------
__global__ __launch_bounds__(256) void k_mean(const float* __restrict__ x,
                                              float* __restrict__ xp) {
    int wave = threadIdx.x >> 6;
    int lane = threadIdx.x & 63;
    int row = blockIdx.x * 4 + wave;         // b*512 + c
    const float4* xr = (const float4*)x + (size_t)row * HW4;
    float s = 0.f;
    #pragma unroll
    for (int k = 0; k < 18; ++k) {
        float4 v = xr[lane + k * 64];
        s += v.x + v.y + v.z + v.w;
    }
    #pragma unroll
    for (int off = 32; off > 0; off >>= 1)
        s += __shfl_down(s, off);
    if (lane == 0) xp[row] = s * (1.0f / (float)HWN);
}

// ---------------------------------------------------------------------------
// Pass 2 (tiny): SE gate; emit gate-folded projection weights.
// ---------------------------------------------------------------------------
__global__ __launch_bounds__(512) void k_gate(
    const float* __restrict__ xp,
    const float* __restrict__ se_w1, const float* __restrict__ se_b1,
    const float* __restrict__ se_w2, const float* __restrict__ se_b2,
    const float* __restrict__ g_w, const float* __restrict__ theta_w,
    const float* __restrict__ phi_w,
    float* __restrict__ tw, float* __restrict__ pw, float* __restrict__ gw) {
    __shared__ float xs[CCH];
    __shared__ float hs[NSE];
    int b = blockIdx.x, t = threadIdx.x;
    int wave = t >> 6, lane = t & 63;
    xs[t] = xp[b * CCH + t];
    __syncthreads();
    #pragma unroll
    for (int i = 0; i < 4; ++i) {
        int h = wave * 4 + i;                // 8 waves x 4 = 32 hidden units
        const float* wr = se_w1 + h * CCH;
        float a = 0.f;
        #pragma unroll
        for (int k = 0; k < 8; ++k)
            a += wr[lane + 64 * k] * xs[lane + 64 * k];
        #pragma unroll
        for (int off = 32; off > 0; off >>= 1)
            a += __shfl_down(a, off);
        if (lane == 0) {
            a += se_b1[h];
            hs[h] = a > 0.f ? a : 0.f;       // relu
        }
    }
    __syncthreads();
    float a = se_b2[t];
    const float* wr = se_w2 + t * NSE;
    #pragma unroll
    for (int j = 0; j < NSE; ++j) a += wr[j] * hs[j];
    float gate = 1.f / (1.f + expf(-a));     // sigmoid
    int idx = b * CCH + t;
    tw[idx] = gate * theta_w[t];
    pw[idx] = gate * phi_w[t];
    gw[idx] = gate * g_w[t];
}

// ---------------------------------------------------------------------------
// Pass 3: partial channel contractions, float4 loads.
// grid (9, 8, 16) = 1152 blocks x 128 thr. 128 float4 p-slots, 64 ch serial.
// ---------------------------------------------------------------------------
__global__ __launch_bounds__(128) void k_proj(
    const float* __restrict__ x,
    const float* __restrict__ tw, const float* __restrict__ pw,
    const float* __restrict__ gw,
    float* __restrict__ th_part, float* __restrict__ ph_part,
    float* __restrict__ gx_part) {
    __shared__ float tws[CPC], pws[CPC], gws[CPC];
    int t = threadIdx.x;
    int b = blockIdx.z;
    int ch = blockIdx.y;
    int c0 = ch * CPC;
    int p4 = blockIdx.x * 128 + t;           // float4 index within row
    if (t < CPC) {
        int wi = b * CCH + c0 + t;
        tws[t] = tw[wi]; pws[t] = pw[wi]; gws[t] = gw[wi];
    }
    __syncthreads();
    const float4* xr = (const float4*)x + (size_t)(b * CCH + c0) * HW4 + p4;
    float4 tha = {0.f, 0.f, 0.f, 0.f};
    float4 pha = {0.f, 0.f, 0.f, 0.f};
    float4 gxa = {0.f, 0.f, 0.f, 0.f};
    #pragma unroll 8
    for (int c = 0; c < CPC; ++c) {
        float4 v = xr[(size_t)c * HW4];      // 128 lanes x 16B contiguous
        float tc = tws[c], pc = pws[c], gc = gws[c];
        tha.x += tc * v.x; tha.y += tc * v.y; tha.z += tc * v.z; tha.w += tc * v.w;
        pha.x += pc * v.x; pha.y += pc * v.y; pha.z += pc * v.z; pha.w += pc * v.w;
        gxa.x += gc * v.x; gxa.y += gc * v.y; gxa.z += gc * v.z; gxa.w += gc * v.w;
    }
    size_t oi = (size_t)(ch * BB + b) * HW4 + p4;
    ((float4*)th_part)[oi] = tha;
    ((float4*)ph_part)[oi] = pha;
    ((float4*)gx_part)[oi] = gxa;
}

// ---------------------------------------------------------------------------
// Pass 4: per-b: s = (1/N) sum_p (pb+PH)(gb+GX); ths = (tb+TH)*s.
// 16 blocks x 512 thr; partials are L2-resident. No cross-block deps.
// ---------------------------------------------------------------------------
__global__ __launch_bounds__(512) void k_sths(
    const float* __restrict__ th_part, const float* __restrict__ ph_part,
    const float* __restrict__ gx_part,
    const float* __restrict__ theta_b, const float* __restrict__ phi_b,
    const float* __restrict__ g_b,
    float* __restrict__ ths) {
    __shared__ float red[8];
    __shared__ float s_sh;
    int b = blockIdx.x, t = threadIdx.x;
    int wave = t >> 6, lane = t & 63;
    float pb = phi_b[0], gb = g_b[0];
    const float4* php = (const float4*)ph_part;
    const float4* gxp = (const float4*)gx_part;
    float acc = 0.f;
    for (int i = t; i < HW4; i += 512) {
        float4 ph = {pb, pb, pb, pb};
        float4 gx = {gb, gb, gb, gb};
        #pragma unroll
        for (int k = 0; k < NCH; ++k) {
            size_t q = (size_t)(k * BB + b) * HW4 + i;
            float4 pv = php[q];
            float4 gv = gxp[q];
            ph.x += pv.x; ph.y += pv.y; ph.z += pv.z; ph.w += pv.w;
            gx.x += gv.x; gx.y += gv.y; gx.z += gv.z; gx.w += gv.w;
        }
        acc += ph.x * gx.x + ph.y * gx.y + ph.z * gx.z + ph.w * gx.w;
    }
    #pragma unroll
    for (int off = 32; off > 0; off >>= 1)
        acc += __shfl_down(acc, off);
    if (lane == 0) red[wave] = acc;
    __syncthreads();
    if (t == 0) {
        float r = 0.f;
        #pragma unroll
        for (int w = 0; w < 8; ++w) r += red[w];
        s_sh = r * (1.0f / (float)HWN);
    }
    __syncthreads();
    float s = s_sh;
    float tb = theta_b[0];
    const float4* thp = (const float4*)th_part;
    for (int i = t; i < HW4; i += 512) {
        float4 th = {tb, tb, tb, tb};
        #pragma unroll
        for (int k = 0; k < NCH; ++k) {
            float4 tv = thp[(size_t)(k * BB + b) * HW4 + i];
            th.x += tv.x; th.y += tv.y; th.z += tv.z; th.w += tv.w;
        }
        float4 o = {th.x * s, th.y * s, th.z * s, th.w * s};
        ((float4*)ths)[(size_t)b * HW4 + i] = o;
    }
}

// ---------------------------------------------------------------------------
// Pass 5: out[b,c,p] = x[b,c,p] + ths[b,p]*A[c] + D[c]
// 2048 blocks x 256 thr, one wave per channel row, nontemporal stores.
// ---------------------------------------------------------------------------
__global__ __launch_bounds__(256) void k_out(
    const float* __restrict__ x, const float* __restrict__ ths,
    const float* __restrict__ W_w, const float* __restrict__ W_b,
    const float* __restrict__ bn_gamma, const float* __restrict__ bn_beta,
    const float* __restrict__ bn_mean, const float* __restrict__ bn_var,
    float* __restrict__ out) {
    int wave = threadIdx.x >> 6;
    int lane = threadIdx.x & 63;
    int c = blockIdx.x * 4 + wave;
    int b = blockIdx.y;
    float inv = bn_gamma[c] * rsqrtf(bn_var[c] + BN_EPS);
    float A = W_w[c] * inv;
    float Dc = (W_b[c] - bn_mean[c]) * inv + bn_beta[c];
    const float4* xr = (const float4*)x + (size_t)(b * CCH + c) * HW4;
    const float4* tr = (const float4*)ths + (size_t)b * HW4;
    f32x4* orow = (f32x4*)out + (size_t)(b * CCH + c) * HW4;
    #pragma unroll
    for (int k = 0; k < 18; ++k) {
        int i = lane + k * 64;
        float4 xv = xr[i];
        float4 tv = tr[i];
        f32x4 o;
        o.x = xv.x + tv.x * A + Dc;
        o.y = xv.y + tv.y * A + Dc;
        o.z = xv.z + tv.z * A + Dc;
        o.w = xv.w + tv.w * A + Dc;
        __builtin_nontemporal_store(o, &orow[i]);
    }
}

// ---------------------------------------------------------------------------
extern "C" void kernel_launch(void* const* d_in, const int* in_sizes, int n_in,
                              void* d_out, int out_size, void* d_ws, size_t ws_size,
                              hipStream_t stream) {
    const float* x       = (const float*)d_in[0];
    const float* se_w1   = (const float*)d_in[1];
    const float* se_b1   = (const float*)d_in[2];
    const float* se_w2   = (const float*)d_in[3];
    const float* se_b2   = (const float*)d_in[4];
    const float* g_w     = (const float*)d_in[5];
    const float* g_b     = (const float*)d_in[6];
    const float* theta_w = (const float*)d_in[7];
    const float* theta_b = (const float*)d_in[8];
    const float* phi_w   = (const float*)d_in[9];
    const float* phi_b   = (const float*)d_in[10];
    const float* W_w     = (const float*)d_in[11];
    const float* W_b     = (const float*)d_in[12];
    const float* bn_g    = (const float*)d_in[13];
    const float* bn_b    = (const float*)d_in[14];
    const float* bn_m    = (const float*)d_in[15];
    const float* bn_v    = (const float*)d_in[16];
    float* out = (float*)d_out;

    // workspace layout (float offsets) — ~7.5 MB of the ~576 MB workspace
    float* ws      = (float*)d_ws;
    float* xp      = ws;                          // 8192
    float* tw      = ws + 8192;                   // 8192
    float* pw      = ws + 16384;                  // 8192
    float* gwv     = ws + 24576;                  // 8192
    float* th_part = ws + 32768;                  // 8*16*4608 = 589824
    float* ph_part = ws + 32768 + 589824;         // 589824
    float* gx_part = ws + 32768 + 2 * 589824;     // 589824
    float* ths     = ws + 32768 + 3 * 589824;     // 73728

    k_mean<<<BB * CCH / 4, 256, 0, stream>>>(x, xp);
    k_gate<<<BB, CCH, 0, stream>>>(xp, se_w1, se_b1, se_w2, se_b2,
                                   g_w, theta_w, phi_w, tw, pw, gwv);
    dim3 gc(9, NCH, BB);
    k_proj<<<gc, 128, 0, stream>>>(x, tw, pw, gwv, th_part, ph_part, gx_part);
    k_sths<<<BB, 512, 0, stream>>>(th_part, ph_part, gx_part,
                                   theta_b, phi_b, g_b, ths);
    dim3 gd(CCH / 4, BB);
    k_out<<<gd, 256, 0, stream>>>(x, ths, W_w, W_b, bn_g, bn_b, bn_m, bn_v, out);
}